// Round 5
// baseline (397.715 us; speedup 1.0000x reference)
//
#include <hip/hip_runtime.h>
#include <hip/hip_bf16.h>
#include <stdint.h>

// GCN layer: out = relu(segment_sum(dropout(x)[src]*w, dst) @ W + b)
// N=50000 nodes, E=800000 edges (dst SORTED), F=512 in/out feats.
//
// Pipeline:
//  1) drop_kernel   : threefry2x32-20 (partitionable) -> xd bf16 [N,512]
//  2) wconv_kernel  : W fp32 [k][n] -> WbT bf16 [n][k]
//  3) rowptr_kernel : CSR row offsets from sorted edge_dst (N+1 entries)
//  4) agg_kernel    : 4 nodes/block (1 wave each), MLP-8 gather ladder,
//                     fp32 acc -> agg bf16 [N,512]   [~3.9 TB/s scatter ceiling]
//  5) gemm_kernel   : MFMA bf16 GEMM, 128x256 tile, 1024 thr (16 waves,
//                     64x32 wave-tiles -> 32 acc VGPR, spill-free), BK=64,
//                     global_load_lds w=16, bias+relu, fp32 out.

#define N_NODESC 50000
#define N_EDGESC 800000
#define FEATS    512
#define TOT_ELEMS (N_NODESC * FEATS)   // 25,600,000

typedef unsigned int u32;
typedef unsigned short u16;
typedef __attribute__((ext_vector_type(8))) short short8;
typedef __attribute__((ext_vector_type(4))) float floatx4;

__device__ __forceinline__ void tf_round(u32& a, u32& b, int r) {
  a += b;
  b = (b << r) | (b >> (32 - r));
  b ^= a;
}

// Threefry-2x32, 20 rounds, key = (0, 42)
__device__ __forceinline__ void threefry(u32& x0, u32& x1) {
  const u32 k0 = 0u, k1 = 42u, k2 = 0x1BD11BDAu ^ 0u ^ 42u;
  x0 += k0; x1 += k1;
  tf_round(x0,x1,13); tf_round(x0,x1,15); tf_round(x0,x1,26); tf_round(x0,x1,6);
  x0 += k1; x1 += k2 + 1u;
  tf_round(x0,x1,17); tf_round(x0,x1,29); tf_round(x0,x1,16); tf_round(x0,x1,24);
  x0 += k2; x1 += k0 + 2u;
  tf_round(x0,x1,13); tf_round(x0,x1,15); tf_round(x0,x1,26); tf_round(x0,x1,6);
  x0 += k0; x1 += k1 + 3u;
  tf_round(x0,x1,17); tf_round(x0,x1,29); tf_round(x0,x1,16); tf_round(x0,x1,24);
  x0 += k1; x1 += k2 + 4u;
  tf_round(x0,x1,13); tf_round(x0,x1,15); tf_round(x0,x1,26); tf_round(x0,x1,6);
  x0 += k2; x1 += k0 + 5u;
}

__device__ __forceinline__ u16 f2bf(float f) {  // RNE float->bf16
  u32 u = __float_as_uint(f);
  u32 r = (u + 0x7FFFu + ((u >> 16) & 1u)) >> 16;
  return (u16)r;
}

// 1) dropout: 4 consecutive flat elements per thread.
__global__ __launch_bounds__(256) void drop_kernel(const float* __restrict__ x,
                                                   u16* __restrict__ xd) {
  int t = blockIdx.x * 256 + threadIdx.x;
  int j0 = t * 4;
  float4 xv = *(const float4*)(x + j0);
  float xs[4] = {xv.x, xv.y, xv.z, xv.w};
  u16 r[4];
#pragma unroll
  for (int q = 0; q < 4; ++q) {
    u32 a = 0u, b = (u32)(j0 + q);
    threefry(a, b);
    u32 bits = a ^ b;
    float u = __uint_as_float((bits >> 9) | 0x3F800000u) - 1.0f;  // [0,1)
    float m = (u < 0.9f) ? (1.0f / 0.9f) : 0.0f;
    r[q] = f2bf(xs[q] * m);
  }
  uint2 o;
  o.x = (u32)r[0] | ((u32)r[1] << 16);
  o.y = (u32)r[2] | ((u32)r[3] << 16);
  *(uint2*)(xd + j0) = o;
}

// 2) W [k][n] fp32 -> WbT [n][k] bf16
__global__ __launch_bounds__(256) void wconv_kernel(const float* __restrict__ W,
                                                    u16* __restrict__ WbT) {
  int t = blockIdx.x * 256 + threadIdx.x;   // 0..262143
  int k = t >> 9, n = t & 511;
  WbT[n * 512 + k] = f2bf(W[t]);
}

// 3) CSR rowptr from sorted dst (covers [0,N] exactly once; N+1 writes total).
__global__ __launch_bounds__(256) void rowptr_kernel(const int* __restrict__ dst,
                                                     int* __restrict__ rowptr) {
  int e = blockIdx.x * 256 + threadIdx.x;
  if (e > N_EDGESC) return;
  int d  = (e < N_EDGESC) ? dst[e] : N_NODESC;
  int pd = (e > 0) ? dst[e - 1] : -1;
  for (int n = pd + 1; n <= d; ++n) rowptr[n] = e;
}

// 4) aggregation: 4 nodes per 256-thread block, one wave per node.
__device__ __forceinline__ void agg_fma(float* acc, float w, const uint4& v) {
  u32 a[4] = {v.x, v.y, v.z, v.w};
#pragma unroll
  for (int p = 0; p < 4; ++p) {
    acc[2*p]   += w * __uint_as_float(a[p] << 16);
    acc[2*p+1] += w * __uint_as_float(a[p] & 0xFFFF0000u);
  }
}

__global__ __launch_bounds__(256) void agg_kernel(const u16* __restrict__ xd,
                                                  const float* __restrict__ ew,
                                                  const int* __restrict__ src,
                                                  const int* __restrict__ rowptr,
                                                  u16* __restrict__ agg) {
  int node = blockIdx.x * 4 + (threadIdx.x >> 6);
  if (node >= N_NODESC) return;
  int lane = threadIdx.x & 63;
  int lo = rowptr[node];
  int hi = rowptr[node + 1];
  float acc[8] = {0.f,0.f,0.f,0.f,0.f,0.f,0.f,0.f};

  int e = lo;
  for (; e + 8 <= hi; e += 8) {
    uint4 v[8]; float w[8];
#pragma unroll
    for (int q = 0; q < 8; ++q) {
      int s = src[e + q];
      w[q] = ew[e + q];
      v[q] = ((const uint4*)(xd + (size_t)s * FEATS))[lane];
    }
#pragma unroll
    for (int q = 0; q < 8; ++q) agg_fma(acc, w[q], v[q]);
  }
  if (e + 4 <= hi) {
    uint4 v[4]; float w[4];
#pragma unroll
    for (int q = 0; q < 4; ++q) {
      int s = src[e + q];
      w[q] = ew[e + q];
      v[q] = ((const uint4*)(xd + (size_t)s * FEATS))[lane];
    }
#pragma unroll
    for (int q = 0; q < 4; ++q) agg_fma(acc, w[q], v[q]);
    e += 4;
  }
  for (; e < hi; ++e) {
    float w = ew[e];
    int s = src[e];
    uint4 v = ((const uint4*)(xd + (size_t)s * FEATS))[lane];
    agg_fma(acc, w, v);
  }

  uint4 o;
  o.x = (u32)f2bf(acc[0]) | ((u32)f2bf(acc[1]) << 16);
  o.y = (u32)f2bf(acc[2]) | ((u32)f2bf(acc[3]) << 16);
  o.z = (u32)f2bf(acc[4]) | ((u32)f2bf(acc[5]) << 16);
  o.w = (u32)f2bf(acc[6]) | ((u32)f2bf(acc[7]) << 16);
  ((uint4*)(agg + (size_t)node * FEATS))[lane] = o;
}

// 5) GEMM: C[M,512] = A[M,512](bf16) * B^T ; relu(+bias).
//    128x256 tile, BK=64, 1024 threads = 16 waves as 2x8 grid of 64x32
//    wave-tiles. acc = 4x2 frags = 32 VGPR -> total ~90-100, no spill at
//    the 128-VGPR cap a 1024-thread block requires.
#define BM 128
#define BN 256
#define BK 64

__global__ __launch_bounds__(1024) void gemm_kernel(const u16* __restrict__ A,
                                                    const u16* __restrict__ BT,
                                                    const float* __restrict__ bias,
                                                    float* __restrict__ out) {
  __shared__ __align__(16) u16 Asm[BM * BK];   // 16 KB
  __shared__ __align__(16) u16 Bsm[BN * BK];   // 32 KB

  const int tid  = threadIdx.x;
  const int lane = tid & 63;
  const int w    = tid >> 6;          // 0..15
  const int m0 = blockIdx.x * BM;
  const int n0 = blockIdx.y * BN;
  const int wm = (w >> 3) * 64;       // 0,64
  const int wn = (w & 7) * 32;        // 0..224
  const int lm   = lane & 15;
  const int quad = lane >> 4;
  const int lrow = lane >> 3;        // 0..7
  const int lcol = (lane & 7) * 8;   // bf16 elems

  floatx4 acc[4][2];
#pragma unroll
  for (int i = 0; i < 4; ++i)
#pragma unroll
    for (int j = 0; j < 2; ++j) acc[i][j] = (floatx4)0.0f;

  for (int k0 = 0; k0 < 512; k0 += BK) {
    // A: 16 chunks (8 rows x 64 cols = 1 KB each); 16 waves x 1
    {
      int chunk = w;                      // 0..15
      int row = chunk * 8 + lrow;         // 0..127
      int gm = m0 + row;
      if (gm > N_NODESC - 1) gm = N_NODESC - 1;
      __builtin_amdgcn_global_load_lds(
          (const __attribute__((address_space(1))) void*)(A + (size_t)gm * 512 + k0 + lcol),
          (__attribute__((address_space(3))) void*)((char*)Asm + chunk * 1024),
          16, 0, 0);
    }
    // B: 32 chunks; 16 waves x 2
#pragma unroll
    for (int t = 0; t < 2; ++t) {
      int chunk = w * 2 + t;              // 0..31
      int row = chunk * 8 + lrow;         // 0..255
      __builtin_amdgcn_global_load_lds(
          (const __attribute__((address_space(1))) void*)(BT + (size_t)(n0 + row) * 512 + k0 + lcol),
          (__attribute__((address_space(3))) void*)((char*)Bsm + chunk * 1024),
          16, 0, 0);
    }
    __syncthreads();

#pragma unroll
    for (int kk = 0; kk < BK; kk += 32) {
      short8 af[4], bfr[2];
#pragma unroll
      for (int i = 0; i < 4; ++i)
        af[i] = *(const short8*)(Asm + (wm + i * 16 + lm) * BK + kk + quad * 8);
#pragma unroll
      for (int j = 0; j < 2; ++j)
        bfr[j] = *(const short8*)(Bsm + (wn + j * 16 + lm) * BK + kk + quad * 8);
#pragma unroll
      for (int i = 0; i < 4; ++i)
#pragma unroll
        for (int j = 0; j < 2; ++j)
          acc[i][j] = __builtin_amdgcn_mfma_f32_16x16x32_bf16(af[i], bfr[j], acc[i][j], 0, 0, 0);
    }
    __syncthreads();
  }

  // epilogue: C/D layout col=lane&15, row=quad*4+r
#pragma unroll
  for (int j = 0; j < 2; ++j) {
    int col = n0 + wn + j * 16 + lm;
    float bv = bias[col];
#pragma unroll
    for (int i = 0; i < 4; ++i) {
      int row0 = m0 + wm + i * 16 + quad * 4;
#pragma unroll
      for (int r = 0; r < 4; ++r) {
        int row = row0 + r;
        if (row < N_NODESC) {
          float v = acc[i][j][r] + bv;
          out[(size_t)row * 512 + col] = v > 0.0f ? v : 0.0f;
        }
      }
    }
  }
}

extern "C" void kernel_launch(void* const* d_in, const int* in_sizes, int n_in,
                              void* d_out, int out_size, void* d_ws, size_t ws_size,
                              hipStream_t stream) {
  const float* x  = (const float*)d_in[0];
  const float* ew = (const float*)d_in[1];
  const float* W  = (const float*)d_in[2];
  const float* b  = (const float*)d_in[3];
  const int* esrc = (const int*)d_in[4];
  const int* edst = (const int*)d_in[5];
  float* out = (float*)d_out;

  char* ws = (char*)d_ws;
  u16* xd    = (u16*)ws;                                   // 51.2 MB
  u16* agg   = (u16*)(ws + (size_t)TOT_ELEMS * 2);         // 51.2 MB
  u16* WbT   = (u16*)(ws + (size_t)TOT_ELEMS * 4);         // 0.5 MB
  int* rowp  = (int*)(ws + (size_t)TOT_ELEMS * 4 + 512 * 512 * 2);  // 200 KB
  (void)ws_size; (void)n_in; (void)in_sizes; (void)out_size;

  hipLaunchKernelGGL(drop_kernel,   dim3(TOT_ELEMS / (256 * 4)), dim3(256), 0, stream, x, xd);
  hipLaunchKernelGGL(wconv_kernel,  dim3((512 * 512) / 256),     dim3(256), 0, stream, W, WbT);
  hipLaunchKernelGGL(rowptr_kernel, dim3((N_EDGESC + 1 + 255) / 256), dim3(256), 0, stream,
                     edst, rowp);
  hipLaunchKernelGGL(agg_kernel,    dim3((N_NODESC + 3) / 4),    dim3(256), 0, stream,
                     xd, ew, esrc, rowp, agg);
  hipLaunchKernelGGL(gemm_kernel,   dim3((N_NODESC + BM - 1) / BM, 512 / BN), dim3(1024), 0, stream,
                     agg, WbT, b, out);
}

// Round 6
// 362.885 us; speedup vs baseline: 1.0960x; 1.0960x over previous
//
#include <hip/hip_runtime.h>
#include <hip/hip_bf16.h>
#include <stdint.h>

// GCN layer: out = relu(segment_sum(dropout(x)[src]*w, dst) @ W + b)
// N=50000 nodes, E=800000 edges (dst SORTED), F=512 in/out feats.
//
// Pipeline:
//  1) prep_kernel   : fused grid-partitioned
//                     [blk 0..12499]     dropout threefry -> xd bf16 [N,512]
//                     [blk 12500..13523] W fp32 [k][n] -> WbT bf16 [n][k]
//                     [blk 13524..16649] CSR rowptr from sorted edge_dst
//  2) agg_kernel    : 4 nodes/block (1 wave each), MLP-8 gather ladder,
//                     fp32 acc -> agg bf16 [N,512]
//                     [~3.3 TB/s LLC-scatter floor; FETCH at compulsory min]
//  3) gemm_kernel   : MFMA bf16 GEMM, 128x256 tile, 512 thr (8 waves,
//                     64x64 wave-tiles, 4x4 frags) — measured-best config (r4).

#define N_NODESC 50000
#define N_EDGESC 800000
#define FEATS    512
#define TOT_ELEMS (N_NODESC * FEATS)   // 25,600,000

#define DROP_BLKS   12500              // 25.6M / (256*8)
#define WCONV_BLKS  1024               // 262144 / 256
#define ROWP_BLKS   3126               // ceil(800001/256)
#define PREP_BLKS   (DROP_BLKS + WCONV_BLKS + ROWP_BLKS)

typedef unsigned int u32;
typedef unsigned short u16;
typedef __attribute__((ext_vector_type(8))) short short8;
typedef __attribute__((ext_vector_type(4))) float floatx4;

__device__ __forceinline__ void tf_round(u32& a, u32& b, int r) {
  a += b;
  b = (b << r) | (b >> (32 - r));
  b ^= a;
}

// Threefry-2x32, 20 rounds, key = (0, 42)
__device__ __forceinline__ void threefry(u32& x0, u32& x1) {
  const u32 k0 = 0u, k1 = 42u, k2 = 0x1BD11BDAu ^ 0u ^ 42u;
  x0 += k0; x1 += k1;
  tf_round(x0,x1,13); tf_round(x0,x1,15); tf_round(x0,x1,26); tf_round(x0,x1,6);
  x0 += k1; x1 += k2 + 1u;
  tf_round(x0,x1,17); tf_round(x0,x1,29); tf_round(x0,x1,16); tf_round(x0,x1,24);
  x0 += k2; x1 += k0 + 2u;
  tf_round(x0,x1,13); tf_round(x0,x1,15); tf_round(x0,x1,26); tf_round(x0,x1,6);
  x0 += k0; x1 += k1 + 3u;
  tf_round(x0,x1,17); tf_round(x0,x1,29); tf_round(x0,x1,16); tf_round(x0,x1,24);
  x0 += k1; x1 += k2 + 4u;
  tf_round(x0,x1,13); tf_round(x0,x1,15); tf_round(x0,x1,26); tf_round(x0,x1,6);
  x0 += k2; x1 += k0 + 5u;
}

__device__ __forceinline__ u16 f2bf(float f) {  // RNE float->bf16
  u32 u = __float_as_uint(f);
  u32 r = (u + 0x7FFFu + ((u >> 16) & 1u)) >> 16;
  return (u16)r;
}

// 1) fused prep: dropout | W transpose+cast | CSR rowptr
__global__ __launch_bounds__(256) void prep_kernel(const float* __restrict__ x,
                                                   u16* __restrict__ xd,
                                                   const float* __restrict__ W,
                                                   u16* __restrict__ WbT,
                                                   const int* __restrict__ dst,
                                                   int* __restrict__ rowptr) {
  int b = blockIdx.x;
  if (b < DROP_BLKS) {
    // dropout: 8 consecutive flat elements per thread
    int t = b * 256 + threadIdx.x;
    int j0 = t * 8;
    float4 xa = *(const float4*)(x + j0);
    float4 xb = *(const float4*)(x + j0 + 4);
    float xs[8] = {xa.x, xa.y, xa.z, xa.w, xb.x, xb.y, xb.z, xb.w};
    u16 r[8];
#pragma unroll
    for (int q = 0; q < 8; ++q) {
      u32 a = 0u, c = (u32)(j0 + q);
      threefry(a, c);
      u32 bits = a ^ c;
      float u = __uint_as_float((bits >> 9) | 0x3F800000u) - 1.0f;  // [0,1)
      float m = (u < 0.9f) ? (1.0f / 0.9f) : 0.0f;
      r[q] = f2bf(xs[q] * m);
    }
    uint4 o;
    o.x = (u32)r[0] | ((u32)r[1] << 16);
    o.y = (u32)r[2] | ((u32)r[3] << 16);
    o.z = (u32)r[4] | ((u32)r[5] << 16);
    o.w = (u32)r[6] | ((u32)r[7] << 16);
    *(uint4*)(xd + j0) = o;
  } else if (b < DROP_BLKS + WCONV_BLKS) {
    // W [k][n] fp32 -> WbT [n][k] bf16
    int t = (b - DROP_BLKS) * 256 + threadIdx.x;   // 0..262143
    int k = t >> 9, n = t & 511;
    WbT[n * 512 + k] = f2bf(W[t]);
  } else {
    // CSR rowptr from sorted dst (covers [0,N] exactly once)
    int e = (b - DROP_BLKS - WCONV_BLKS) * 256 + threadIdx.x;
    if (e > N_EDGESC) return;
    int d  = (e < N_EDGESC) ? dst[e] : N_NODESC;
    int pd = (e > 0) ? dst[e - 1] : -1;
    for (int n = pd + 1; n <= d; ++n) rowptr[n] = e;
  }
}

// 2) aggregation: 4 nodes per 256-thread block, one wave per node.
__device__ __forceinline__ void agg_fma(float* acc, float w, const uint4& v) {
  u32 a[4] = {v.x, v.y, v.z, v.w};
#pragma unroll
  for (int p = 0; p < 4; ++p) {
    acc[2*p]   += w * __uint_as_float(a[p] << 16);
    acc[2*p+1] += w * __uint_as_float(a[p] & 0xFFFF0000u);
  }
}

__global__ __launch_bounds__(256) void agg_kernel(const u16* __restrict__ xd,
                                                  const float* __restrict__ ew,
                                                  const int* __restrict__ src,
                                                  const int* __restrict__ rowptr,
                                                  u16* __restrict__ agg) {
  int node = blockIdx.x * 4 + (threadIdx.x >> 6);
  if (node >= N_NODESC) return;
  int lane = threadIdx.x & 63;
  int lo = rowptr[node];
  int hi = rowptr[node + 1];
  float acc[8] = {0.f,0.f,0.f,0.f,0.f,0.f,0.f,0.f};

  int e = lo;
  for (; e + 8 <= hi; e += 8) {
    uint4 v[8]; float w[8];
#pragma unroll
    for (int q = 0; q < 8; ++q) {
      int s = src[e + q];
      w[q] = ew[e + q];
      v[q] = ((const uint4*)(xd + (size_t)s * FEATS))[lane];
    }
#pragma unroll
    for (int q = 0; q < 8; ++q) agg_fma(acc, w[q], v[q]);
  }
  if (e + 4 <= hi) {
    uint4 v[4]; float w[4];
#pragma unroll
    for (int q = 0; q < 4; ++q) {
      int s = src[e + q];
      w[q] = ew[e + q];
      v[q] = ((const uint4*)(xd + (size_t)s * FEATS))[lane];
    }
#pragma unroll
    for (int q = 0; q < 4; ++q) agg_fma(acc, w[q], v[q]);
    e += 4;
  }
  for (; e < hi; ++e) {
    float w = ew[e];
    int s = src[e];
    uint4 v = ((const uint4*)(xd + (size_t)s * FEATS))[lane];
    agg_fma(acc, w, v);
  }

  uint4 o;
  o.x = (u32)f2bf(acc[0]) | ((u32)f2bf(acc[1]) << 16);
  o.y = (u32)f2bf(acc[2]) | ((u32)f2bf(acc[3]) << 16);
  o.z = (u32)f2bf(acc[4]) | ((u32)f2bf(acc[5]) << 16);
  o.w = (u32)f2bf(acc[6]) | ((u32)f2bf(acc[7]) << 16);
  ((uint4*)(agg + (size_t)node * FEATS))[lane] = o;
}

// 3) GEMM: C[M,512] = A[M,512](bf16) * B^T ; relu(+bias).
//    128x256 tile, BK=64, 512 threads = 8 waves as 2x4 grid of 64x64 tiles.
//    (measured-best config: r4; 256-thr/128x128 and 1024-thr/64x32 both slower)
#define BM 128
#define BN 256
#define BK 64

__global__ __launch_bounds__(512, 4) void gemm_kernel(const u16* __restrict__ A,
                                                      const u16* __restrict__ BT,
                                                      const float* __restrict__ bias,
                                                      float* __restrict__ out) {
  __shared__ __align__(16) u16 Asm[BM * BK];   // 16 KB
  __shared__ __align__(16) u16 Bsm[BN * BK];   // 32 KB

  const int tid  = threadIdx.x;
  const int lane = tid & 63;
  const int w    = tid >> 6;          // 0..7
  const int m0 = blockIdx.x * BM;
  const int n0 = blockIdx.y * BN;
  const int wm = (w >> 2) * 64;       // 0,64
  const int wn = (w & 3) * 64;        // 0,64,128,192
  const int lm   = lane & 15;
  const int quad = lane >> 4;
  const int lrow = lane >> 3;        // 0..7
  const int lcol = (lane & 7) * 8;   // bf16 elems

  floatx4 acc[4][4];
#pragma unroll
  for (int i = 0; i < 4; ++i)
#pragma unroll
    for (int j = 0; j < 4; ++j) acc[i][j] = (floatx4)0.0f;

  for (int k0 = 0; k0 < 512; k0 += BK) {
    // A: 16 chunks (8 rows x 64 cols = 1 KB each); 8 waves x 2
#pragma unroll
    for (int t = 0; t < 2; ++t) {
      int chunk = w * 2 + t;              // 0..15
      int row = chunk * 8 + lrow;         // 0..127
      int gm = m0 + row;
      if (gm > N_NODESC - 1) gm = N_NODESC - 1;
      __builtin_amdgcn_global_load_lds(
          (const __attribute__((address_space(1))) void*)(A + (size_t)gm * 512 + k0 + lcol),
          (__attribute__((address_space(3))) void*)((char*)Asm + chunk * 1024),
          16, 0, 0);
    }
    // B: 32 chunks; 8 waves x 4
#pragma unroll
    for (int t = 0; t < 4; ++t) {
      int chunk = w * 4 + t;              // 0..31
      int row = chunk * 8 + lrow;         // 0..255
      __builtin_amdgcn_global_load_lds(
          (const __attribute__((address_space(1))) void*)(BT + (size_t)(n0 + row) * 512 + k0 + lcol),
          (__attribute__((address_space(3))) void*)((char*)Bsm + chunk * 1024),
          16, 0, 0);
    }
    __syncthreads();

#pragma unroll
    for (int kk = 0; kk < BK; kk += 32) {
      short8 af[4], bfr[4];
#pragma unroll
      for (int i = 0; i < 4; ++i)
        af[i] = *(const short8*)(Asm + (wm + i * 16 + lm) * BK + kk + quad * 8);
#pragma unroll
      for (int j = 0; j < 4; ++j)
        bfr[j] = *(const short8*)(Bsm + (wn + j * 16 + lm) * BK + kk + quad * 8);
#pragma unroll
      for (int i = 0; i < 4; ++i)
#pragma unroll
        for (int j = 0; j < 4; ++j)
          acc[i][j] = __builtin_amdgcn_mfma_f32_16x16x32_bf16(af[i], bfr[j], acc[i][j], 0, 0, 0);
    }
    __syncthreads();
  }

  // epilogue: C/D layout col=lane&15, row=quad*4+r
#pragma unroll
  for (int j = 0; j < 4; ++j) {
    int col = n0 + wn + j * 16 + lm;
    float bv = bias[col];
#pragma unroll
    for (int i = 0; i < 4; ++i) {
      int row0 = m0 + wm + i * 16 + quad * 4;
#pragma unroll
      for (int r = 0; r < 4; ++r) {
        int row = row0 + r;
        if (row < N_NODESC) {
          float v = acc[i][j][r] + bv;
          out[(size_t)row * 512 + col] = v > 0.0f ? v : 0.0f;
        }
      }
    }
  }
}

extern "C" void kernel_launch(void* const* d_in, const int* in_sizes, int n_in,
                              void* d_out, int out_size, void* d_ws, size_t ws_size,
                              hipStream_t stream) {
  const float* x  = (const float*)d_in[0];
  const float* ew = (const float*)d_in[1];
  const float* W  = (const float*)d_in[2];
  const float* b  = (const float*)d_in[3];
  const int* esrc = (const int*)d_in[4];
  const int* edst = (const int*)d_in[5];
  float* out = (float*)d_out;

  char* ws = (char*)d_ws;
  u16* xd    = (u16*)ws;                                   // 51.2 MB
  u16* agg   = (u16*)(ws + (size_t)TOT_ELEMS * 2);         // 51.2 MB
  u16* WbT   = (u16*)(ws + (size_t)TOT_ELEMS * 4);         // 0.5 MB
  int* rowp  = (int*)(ws + (size_t)TOT_ELEMS * 4 + 512 * 512 * 2);  // 200 KB
  (void)ws_size; (void)n_in; (void)in_sizes; (void)out_size;

  hipLaunchKernelGGL(prep_kernel,  dim3(PREP_BLKS), dim3(256), 0, stream,
                     x, xd, W, WbT, edst, rowp);
  hipLaunchKernelGGL(agg_kernel,   dim3((N_NODESC + 3) / 4), dim3(256), 0, stream,
                     xd, ew, esrc, rowp, agg);
  hipLaunchKernelGGL(gemm_kernel,  dim3((N_NODESC + BM - 1) / BM, 512 / BN), dim3(512), 0, stream,
                     agg, WbT, b, out);
}